// Round 12
// baseline (168.046 us; speedup 1.0000x reference)
//
#include <hip/hip_runtime.h>
#include <hip/hip_bf16.h>
#include <math.h>

#define B_ 2
#define N_ 4096          // H*W*D
#define BN_ 8192
#define NH_ 4
#define SPLIT_ 8         // attention K-split (in-block: 8 waves = 8 splits)

using bf16x8   = __attribute__((ext_vector_type(8))) __bf16;
using f32x4    = __attribute__((ext_vector_type(4))) float;
using ushortx8 = __attribute__((ext_vector_type(8))) unsigned short;

#if __has_builtin(__builtin_amdgcn_exp2f)
#define FAST_EXP2(x) __builtin_amdgcn_exp2f(x)
#else
#define FAST_EXP2(x) __expf((x) * 0.6931471805599453f)
#endif

static __device__ __forceinline__ unsigned short f2bf(float f) {
    union { __hip_bfloat16 h; unsigned short u; } c;
    c.h = __float2bfloat16(f);
    return c.u;
}
static __device__ __forceinline__ float bf2f(unsigned short u) {
    union { __hip_bfloat16 h; unsigned short u; } c;
    c.u = u;
    return __bfloat162float(c.h);
}
// pack two f32 -> two bf16 (round-biased truncate) in one v_perm_b32
static __device__ __forceinline__ unsigned int pk2bf(float lo, float hi) {
    return __builtin_amdgcn_perm(__float_as_uint(hi) + 0x8000u,
                                 __float_as_uint(lo) + 0x8000u, 0x07060302u);
}
// load 8 fp32 weights, convert to a bf16 A/B fragment in-register
static __device__ __forceinline__ bf16x8 ldw(const float* __restrict__ W, size_t off) {
    const float4 a = *(const float4*)(W + off);
    const float4 b = *(const float4*)(W + off + 4);
    union { uint4 u; bf16x8 v; } c;
    c.u.x = pk2bf(a.x, a.y); c.u.y = pk2bf(a.z, a.w);
    c.u.z = pk2bf(b.x, b.y); c.u.w = pk2bf(b.z, b.w);
    return c.v;
}

// ---------------------------------------------------------------------------
// QKV v5: LDS-staged LN + projection, inline fp32->bf16 weight conversion.
// Blocks 0..767: z = gid/256 (0 Q/dec, 1 K/enc, 2 V/enc), 32 tokens each,
// every wave does 4 nb (16-MFMA chain). Blocks 768..839 convert wo/w1/w2.
// ---------------------------------------------------------------------------
__global__ __launch_bounds__(256)
void qkv4_kernel(const float* __restrict__ enc, const float* __restrict__ dec,
                 const float* __restrict__ g_enc, const float* __restrict__ b_enc,
                 const float* __restrict__ g_dec, const float* __restrict__ b_dec,
                 const float* __restrict__ Wq, const float* __restrict__ Wk,
                 const float* __restrict__ Wv,
                 const float* __restrict__ bq, const float* __restrict__ bk,
                 const float* __restrict__ bv,
                 const float* __restrict__ Wo, const float* __restrict__ W1,
                 const float* __restrict__ W2,
                 unsigned short* __restrict__ wo, unsigned short* __restrict__ w1,
                 unsigned short* __restrict__ w2,
                 unsigned short* __restrict__ Qh, unsigned short* __restrict__ Kh,
                 unsigned short* __restrict__ Vt,
                 unsigned short* __restrict__ dec_lnb) {
    const int t = threadIdx.x;
    if (blockIdx.x >= 768) {
        // ---- weight conversion for the tail: wo(16384) w1(65536) w2(65536)
        const int e = ((int)blockIdx.x - 768) * 2048 + t * 8;
        const float* src; unsigned short* dst; int off;
        if (e < 16384)       { src = Wo; dst = wo; off = e; }
        else if (e < 81920)  { src = W1; dst = w1; off = e - 16384; }
        else                 { src = W2; dst = w2; off = e - 81920; }
        const float4 a = *(const float4*)(src + off);
        const float4 b = *(const float4*)(src + off + 4);
        uint4 p;
        p.x = pk2bf(a.x, a.y); p.y = pk2bf(a.z, a.w);
        p.z = pk2bf(b.x, b.y); p.w = pk2bf(b.z, b.w);
        *(uint4*)(dst + off) = p;
        return;
    }
    __shared__ float tile[128][33];
    __shared__ float mu_s[32], inv_s[32];
    const int z  = blockIdx.x >> 8;       // 0 Q/dec, 1 K/enc, 2 V/enc
    const int m0 = (blockIdx.x & 255) * 32;
    const int b  = m0 >> 12, n0 = m0 & 4095;
    const float* inb   = ((z == 0) ? dec : enc) + (size_t)b * 128 * N_;
    const float* gamma = (z == 0) ? g_dec : g_enc;
    const float* beta  = (z == 0) ? b_dec : b_enc;

    // stage: 128 chans x 32 tokens, 128B-coalesced along n
    {
        const int col = t & 31;
        const int r0  = t >> 5;
        #pragma unroll
        for (int j = 0; j < 16; ++j) {
            const int r = r0 + 8 * j;
            tile[r][col] = inb[(size_t)r * N_ + n0 + col];
        }
    }
    __syncthreads();
    // LN stats: 8 threads per token
    {
        const int tok = t >> 3;
        const int ln  = t & 7;
        float s = 0.f, ss = 0.f;
        for (int c = ln; c < 128; c += 8) {
            const float x = tile[c][tok];
            s += x; ss += x * x;
        }
        for (int m = 1; m < 8; m <<= 1) {
            s  += __shfl_xor(s, m);
            ss += __shfl_xor(ss, m);
        }
        if (ln == 0) {
            const float mu  = s * (1.f / 128.f);
            mu_s[tok]  = mu;
            inv_s[tok] = rsqrtf(ss * (1.f / 128.f) - mu * mu + 1e-5f);
        }
    }
    __syncthreads();

    const int wvx = t >> 6, lane = t & 63;
    const int l15 = lane & 15, quad = lane >> 4;
    const int tokgrp  = (wvx & 1) * 16;
    const int colbase = (wvx >> 1) * 64;
    const bool wrLN   = (z == 0) && ((wvx >> 1) == 0);
    const int tok = tokgrp + l15;
    const float mu  = mu_s[tok];
    const float inv = inv_s[tok];

    // build LN'd A-frags straight from LDS
    bf16x8 af[4];
    #pragma unroll
    for (int kk = 0; kk < 4; ++kk) {
        float y[8];
        #pragma unroll
        for (int j = 0; j < 8; ++j) {
            const int c = kk * 32 + quad * 8 + j;
            y[j] = (tile[c][tok] - mu) * inv * gamma[c] + beta[c];
        }
        union { uint4 u; bf16x8 v8; ushortx8 us; } cvt;
        cvt.u.x = pk2bf(y[0], y[1]); cvt.u.y = pk2bf(y[2], y[3]);
        cvt.u.z = pk2bf(y[4], y[5]); cvt.u.w = pk2bf(y[6], y[7]);
        af[kk] = cvt.v8;
        if (wrLN)
            *(ushortx8*)(dec_lnb + (size_t)(m0 + tok) * 128 + kk * 32 + quad * 8) = cvt.us;
    }

    const float* Wb   = (z == 0) ? Wq : ((z == 1) ? Wk : Wv);
    const float* bias = (z == 0) ? bq : ((z == 1) ? bk : bv);
    const float sc = (z == 0) ? (0.17677669529663687f * 1.4426950408889634f) : 1.f;
    const int nbase = n0 + tokgrp + quad * 4;

    #pragma unroll
    for (int nb = 0; nb < 4; ++nb) {
        const int col = colbase + nb * 16 + l15;
        f32x4 a = {0.f, 0.f, 0.f, 0.f};
        #pragma unroll
        for (int kk = 0; kk < 4; ++kk) {
            const bf16x8 wf = ldw(Wb, (size_t)col * 128 + kk * 32 + quad * 8);
            a = __builtin_amdgcn_mfma_f32_16x16x32_bf16(af[kk], wf, a, 0, 0, 0);
        }
        const int h = col >> 5, d = col & 31;
        const float bz = bias[col];
        if (z == 2) {
            ushort4 pk;
            pk.x = f2bf(a[0] + bz);
            pk.y = f2bf(a[1] + bz);
            pk.z = f2bf(a[2] + bz);
            pk.w = f2bf(a[3] + bz);
            *(ushort4*)(Vt + ((size_t)(b * NH_ + h) * 32 + d) * N_ + nbase) = pk;
        } else {
            unsigned short* dst = (z == 0) ? Qh : Kh;
            #pragma unroll
            for (int r = 0; r < 4; ++r)
                dst[((size_t)(b * NH_ + h) * N_ + nbase + r) * 32 + d] = f2bf((a[r] + bz) * sc);
        }
    }
}

// ---------------------------------------------------------------------------
// Attention v7 (R11-proven): split-K IN-BLOCK. 512-thr block = 8 waves =
// 8 K-splits of the SAME 64 queries; fp32 combine via LDS (reusing sP) ->
// final bf16 ctx write. Grid 512, XCD-affine (gid&7 == bh).
// ---------------------------------------------------------------------------
__global__ __launch_bounds__(512)
void attn_kernel7(const unsigned short* __restrict__ Qh,
                  const unsigned short* __restrict__ Kh,
                  const unsigned short* __restrict__ Vt,
                  unsigned short* __restrict__ ctx) {
    __shared__ alignas(16) unsigned short sP[8][64][72];  // 73728 B; reused fp32 [8][64][36]
    __shared__ float ldsL[8][64];

    const int gid  = blockIdx.x;
    const int bh   = gid & 7;
    const int qblk = gid >> 3;          // 0..63
    const int t  = threadIdx.x;
    const int wvx = t >> 6, lane = t & 63;
    const int l15 = lane & 15, quad = lane >> 4;
    const int s = wvx;
    const int qw = qblk * 64;
    const size_t hbse = (size_t)bh * N_ * 32;

    bf16x8 qf[4];
    #pragma unroll
    for (int f = 0; f < 4; ++f)
        qf[f] = *(const bf16x8*)(Qh + hbse + (size_t)(qw + f * 16 + l15) * 32 + quad * 8);

    const unsigned short* Kp = Kh + hbse;
    const unsigned short* Vp = Vt + (size_t)bh * 32 * N_;

    f32x4 o0[4], o1[4];
    float l[4];
    #pragma unroll
    for (int f = 0; f < 4; ++f) {
        o0[f] = f32x4{0.f, 0.f, 0.f, 0.f};
        o1[f] = f32x4{0.f, 0.f, 0.f, 0.f};
        l[f] = 0.f;
    }
    const f32x4 zero = {0.f, 0.f, 0.f, 0.f};

    const int kbeg = s * (N_ / SPLIT_);
    const int kend = kbeg + (N_ / SPLIT_);

    bf16x8 kf[4];
    #pragma unroll
    for (int c = 0; c < 4; ++c)
        kf[c] = *(const bf16x8*)(Kp + (size_t)(kbeg + c * 16 + l15) * 32 + quad * 8);

    for (int k0 = kbeg; k0 < kend; k0 += 64) {
        bf16x8 va[2], vb[2];
        #pragma unroll
        for (int s2 = 0; s2 < 2; ++s2) {
            va[s2] = *(const bf16x8*)(Vp + (size_t)l15 * N_        + k0 + s2 * 32 + quad * 8);
            vb[s2] = *(const bf16x8*)(Vp + (size_t)(16 + l15) * N_ + k0 + s2 * 32 + quad * 8);
        }
        const int kn = (k0 + 64 < kend) ? (k0 + 64) : kbeg;
        bf16x8 kfn[4];
        #pragma unroll
        for (int c = 0; c < 4; ++c)
            kfn[c] = *(const bf16x8*)(Kp + (size_t)(kn + c * 16 + l15) * 32 + quad * 8);

        #pragma unroll
        for (int f = 0; f < 4; ++f) {
            #pragma unroll
            for (int c = 0; c < 4; ++c) {
                const f32x4 sv = __builtin_amdgcn_mfma_f32_16x16x32_bf16(kf[c], qf[f], zero, 0, 0, 0);
                const float p0 = FAST_EXP2(sv[0]);
                const float p1 = FAST_EXP2(sv[1]);
                const float p2 = FAST_EXP2(sv[2]);
                const float p3 = FAST_EXP2(sv[3]);
                l[f] += (p0 + p1) + (p2 + p3);
                uint2 pk;
                pk.x = pk2bf(p0, p1);
                pk.y = pk2bf(p2, p3);
                *(uint2*)&sP[wvx][f * 16 + l15][c * 16 + quad * 4] = pk;
            }
        }
        #pragma unroll
        for (int f = 0; f < 4; ++f) {
            #pragma unroll
            for (int s2 = 0; s2 < 2; ++s2) {
                const bf16x8 pf = *(const bf16x8*)&sP[wvx][f * 16 + l15][s2 * 32 + quad * 8];
                o0[f] = __builtin_amdgcn_mfma_f32_16x16x32_bf16(va[s2], pf, o0[f], 0, 0, 0);
                o1[f] = __builtin_amdgcn_mfma_f32_16x16x32_bf16(vb[s2], pf, o1[f], 0, 0, 0);
            }
        }
        #pragma unroll
        for (int c = 0; c < 4; ++c) kf[c] = kfn[c];
    }

    float lf4[4];
    #pragma unroll
    for (int f = 0; f < 4; ++f) {
        float lf = l[f];
        lf += __shfl_xor(lf, 16);
        lf += __shfl_xor(lf, 32);
        lf4[f] = lf;
    }

    __syncthreads();
    float* ldsO = (float*)&sP[0][0][0];   // [8][64][36]
    #pragma unroll
    for (int f = 0; f < 4; ++f) {
        const int q = f * 16 + l15;
        float* row = ldsO + ((size_t)s * 64 + q) * 36;
        *(f32x4*)(row + quad * 4)      = o0[f];
        *(f32x4*)(row + 16 + quad * 4) = o1[f];
        if (quad == 0) ldsL[s][q] = lf4[f];
    }
    __syncthreads();

    const int tok = t >> 3;
    const int d0  = (t & 7) * 4;
    f32x4 sum = {0.f, 0.f, 0.f, 0.f};
    float lsum = 0.f;
    #pragma unroll
    for (int w = 0; w < 8; ++w) {
        sum  += *(const f32x4*)(ldsO + ((size_t)w * 64 + tok) * 36 + d0);
        lsum += ldsL[w][tok];
    }
    const float inv = 1.f / lsum;
    uint2 pk;
    pk.x = pk2bf(sum[0] * inv, sum[1] * inv);
    pk.y = pk2bf(sum[2] * inv, sum[3] * inv);
    const int b = bh >> 2, h = bh & 3;
    *(uint2*)(ctx + ((size_t)(b * N_ + qw + tok)) * 128 + h * 32 + d0) = pk;
}

// ---------------------------------------------------------------------------
// Fused tail v5: COLUMN-split, full-K per wave (no partial reductions).
// Wo: wave owns 32 out-cols, full K=128 from ctx -> out1 in regs directly.
// LN: cross-wave stats via sln (2 barriers). FFN1: wave owns 128 cols.
// FFN2: wave owns 32 out-cols, full K=512 from smid -> direct store.
// Barriers 5->3; LDS 21.5 KB -> 7 blocks/CU; fp32 accumulation throughout.
// 512 blocks x 16 tokens x 256 thr.
// ---------------------------------------------------------------------------
__global__ __launch_bounds__(256)
void fused_tail5_kernel(const unsigned short* __restrict__ ctx,
                        const unsigned short* __restrict__ wo,
                        const float* __restrict__ bo,
                        const unsigned short* __restrict__ decb,
                        const float* __restrict__ g, const float* __restrict__ be,
                        const unsigned short* __restrict__ w1,
                        const float* __restrict__ b1,
                        const unsigned short* __restrict__ w2,
                        const float* __restrict__ b2,
                        float* __restrict__ out) {
    __shared__ float sln[4][2][16];                            // 0.5 KB
    __shared__ alignas(16) unsigned short hb_lds[16][136];     // 4.25 KB
    __shared__ alignas(16) unsigned short smid[16][536];       // 16.75 KB
    const int t = threadIdx.x;
    const int wv = t >> 6, lane = t & 63;
    const int l15 = lane & 15, quad = lane >> 4;
    const int m0 = blockIdx.x * 16;

    // ---- A-frags: full 128 chans of this token (4 x 16B loads)
    const int tokA = m0 + l15;
    bf16x8 af[4];
    #pragma unroll
    for (int kk = 0; kk < 4; ++kk)
        af[kk] = *(const bf16x8*)(ctx + (size_t)tokA * 128 + kk * 32 + quad * 8);

    // ---- Wo full-K: wave owns cols [wv*32, wv*32+32) -> out1 in regs
    float v[2][4];
    #pragma unroll
    for (int lnb = 0; lnb < 2; ++lnb) {
        const int col = (2 * wv + lnb) * 16 + l15;
        f32x4 a = {0.f, 0.f, 0.f, 0.f};
        #pragma unroll
        for (int kk = 0; kk < 4; ++kk) {
            const bf16x8 wf = *(const bf16x8*)(wo + (size_t)col * 128 + kk * 32 + quad * 8);
            a = __builtin_amdgcn_mfma_f32_16x16x32_bf16(af[kk], wf, a, 0, 0, 0);
        }
        const float bz = bo[col];
        #pragma unroll
        for (int r = 0; r < 4; ++r) {
            const int tok = m0 + quad * 4 + r;
            v[lnb][r] = a[r] + bz + bf2f(decb[(size_t)tok * 128 + col]);
        }
    }

    // ---- LN partial sums over this wave's 32 cols
    {
        float s[4], ss[4];
        #pragma unroll
        for (int r = 0; r < 4; ++r) {
            float a = v[0][r] + v[1][r];
            float b = v[0][r] * v[0][r] + v[1][r] * v[1][r];
            for (int m = 1; m < 16; m <<= 1) {
                a += __shfl_xor(a, m);
                b += __shfl_xor(b, m);
            }
            s[r] = a; ss[r] = b;
        }
        if (l15 == 0) {
            #pragma unroll
            for (int r = 0; r < 4; ++r) {
                sln[wv][0][quad * 4 + r] = s[r];
                sln[wv][1][quad * 4 + r] = ss[r];
            }
        }
    }
    __syncthreads();

    // ---- full LN stats, normalize own 32 cols -> hb_lds
    {
        #pragma unroll
        for (int r = 0; r < 4; ++r) {
            const int tk = quad * 4 + r;
            const float stot  = sln[0][0][tk] + sln[1][0][tk] + sln[2][0][tk] + sln[3][0][tk];
            const float sstot = sln[0][1][tk] + sln[1][1][tk] + sln[2][1][tk] + sln[3][1][tk];
            const float mu  = stot * (1.f / 128.f);
            const float inv = rsqrtf(sstot * (1.f / 128.f) - mu * mu + 1e-5f);
            #pragma unroll
            for (int lnb = 0; lnb < 2; ++lnb) {
                const int col = (2 * wv + lnb) * 16 + l15;
                hb_lds[tk][col] = f2bf((v[lnb][r] - mu) * inv * g[col] + be[col]);
            }
        }
    }
    __syncthreads();

    // ---- FFN1: wave owns cols [wv*128, wv*128+128), full K=128
    bf16x8 hf[4];
    #pragma unroll
    for (int kk = 0; kk < 4; ++kk)
        hf[kk] = *(const bf16x8*)&hb_lds[l15][kk * 32 + quad * 8];
    #pragma unroll
    for (int nb = 0; nb < 8; ++nb) {
        const int col = wv * 128 + nb * 16 + l15;
        f32x4 a = {0.f, 0.f, 0.f, 0.f};
        #pragma unroll
        for (int kk = 0; kk < 4; ++kk) {
            const bf16x8 wf = *(const bf16x8*)(w1 + (size_t)col * 128 + kk * 32 + quad * 8);
            a = __builtin_amdgcn_mfma_f32_16x16x32_bf16(hf[kk], wf, a, 0, 0, 0);
        }
        const float bz = b1[col];
        #pragma unroll
        for (int r = 0; r < 4; ++r) {
            float x = a[r] + bz;
            x = 0.5f * x * (1.f + erff(x * 0.70710678118f));
            smid[quad * 4 + r][col] = f2bf(x);
        }
    }
    __syncthreads();

    // ---- FFN2: wave owns out-cols [wv*32, wv*32+32), full K=512, direct store
    const int b = m0 >> 12;
    const int nb0 = (m0 & 4095) + quad * 4;
    #pragma unroll
    for (int lnb = 0; lnb < 2; ++lnb) {
        const int col = (2 * wv + lnb) * 16 + l15;
        f32x4 a = {0.f, 0.f, 0.f, 0.f};
        #pragma unroll
        for (int kk = 0; kk < 16; ++kk) {
            const bf16x8 af2 = *(const bf16x8*)&smid[l15][kk * 32 + quad * 8];
            const bf16x8 wf  = *(const bf16x8*)(w2 + (size_t)col * 512 + kk * 32 + quad * 8);
            a = __builtin_amdgcn_mfma_f32_16x16x32_bf16(af2, wf, a, 0, 0, 0);
        }
        const float bz = b2[col];
        f32x4 res;
        #pragma unroll
        for (int r = 0; r < 4; ++r)
            res[r] = a[r] + bz + v[lnb][r];
        *(f32x4*)&out[((size_t)(b * 128 + col)) * N_ + nb0] = res;
    }
}

// ---------------------------------------------------------------------------
extern "C" void kernel_launch(void* const* d_in, const int* in_sizes, int n_in,
                              void* d_out, int out_size, void* d_ws, size_t ws_size,
                              hipStream_t stream) {
    const float* enc   = (const float*)d_in[0];
    const float* dec   = (const float*)d_in[1];
    const float* Wq    = (const float*)d_in[2];
    const float* bq    = (const float*)d_in[3];
    const float* Wk    = (const float*)d_in[4];
    const float* bk    = (const float*)d_in[5];
    const float* Wv    = (const float*)d_in[6];
    const float* bv    = (const float*)d_in[7];
    const float* Wo    = (const float*)d_in[8];
    const float* bo    = (const float*)d_in[9];
    const float* g_enc = (const float*)d_in[10];
    const float* b_enc = (const float*)d_in[11];
    const float* g_dec = (const float*)d_in[12];
    const float* b_dec = (const float*)d_in[13];
    const float* g_out = (const float*)d_in[14];
    const float* b_out = (const float*)d_in[15];
    const float* W1    = (const float*)d_in[16];
    const float* b1    = (const float*)d_in[17];
    const float* W2    = (const float*)d_in[18];
    const float* b2    = (const float*)d_in[19];
    float* out = (float*)d_out;
    char*  W   = (char*)d_ws;

    // workspace layout (<= 13 MB, subset of prior passing footprint)
    unsigned short* wob = (unsigned short*)(W);          // 32 KB
    unsigned short* w1b = wob + 16384;                   // 128 KB
    unsigned short* w2b = w1b + 65536;                   // 128 KB (ends 288 KB)
    unsigned short* dec_lnb = (unsigned short*)(W + (2560ull << 10));   // [2.5, 4.5) MB
    unsigned short* Qh      = (unsigned short*)(W + (4608ull << 10));   // [4.5, 6.5)
    unsigned short* Kh      = (unsigned short*)(W + (6656ull << 10));   // [6.5, 8.5)
    unsigned short* Vt      = (unsigned short*)(W + (8704ull << 10));   // [8.5, 10.5)
    unsigned short* ctx     = (unsigned short*)(W + (10752ull << 10));  // 2 MB

    // QKV (+inline LN, inline wq/wk/wv cvt) + tail-weight conversion blocks
    qkv4_kernel<<<768 + 72, 256, 0, stream>>>(
        enc, dec, g_enc, b_enc, g_dec, b_dec, Wq, Wk, Wv, bq, bk, bv,
        Wo, W1, W2, wob, w1b, w2b, Qh, Kh, Vt, dec_lnb);

    // 512 blocks x 512 thr, XCD-affine (gid&7 == bh); in-block split combine
    attn_kernel7<<<512, 512, 0, stream>>>(Qh, Kh, Vt, ctx);

    fused_tail5_kernel<<<512, 256, 0, stream>>>(ctx, wob, bo, dec_lnb,
                                                g_out, b_out, w1b, b1, w2b, b2, out);
}

// Round 13
// 164.020 us; speedup vs baseline: 1.0245x; 1.0245x over previous
//
#include <hip/hip_runtime.h>
#include <hip/hip_bf16.h>
#include <math.h>

#define B_ 2
#define N_ 4096          // H*W*D
#define BN_ 8192
#define NH_ 4
#define SPLIT_ 8         // attention K-split (in-block: 8 waves = 8 splits)

using bf16x8   = __attribute__((ext_vector_type(8))) __bf16;
using f32x4    = __attribute__((ext_vector_type(4))) float;
using ushortx8 = __attribute__((ext_vector_type(8))) unsigned short;

#if __has_builtin(__builtin_amdgcn_exp2f)
#define FAST_EXP2(x) __builtin_amdgcn_exp2f(x)
#else
#define FAST_EXP2(x) __expf((x) * 0.6931471805599453f)
#endif

static __device__ __forceinline__ unsigned short f2bf(float f) {
    union { __hip_bfloat16 h; unsigned short u; } c;
    c.h = __float2bfloat16(f);
    return c.u;
}
static __device__ __forceinline__ float bf2f(unsigned short u) {
    union { __hip_bfloat16 h; unsigned short u; } c;
    c.u = u;
    return __bfloat162float(c.h);
}
// pack two f32 -> two bf16 (round-biased truncate) in one v_perm_b32
static __device__ __forceinline__ unsigned int pk2bf(float lo, float hi) {
    return __builtin_amdgcn_perm(__float_as_uint(hi) + 0x8000u,
                                 __float_as_uint(lo) + 0x8000u, 0x07060302u);
}
// load 8 fp32 weights, convert to a bf16 A/B fragment in-register
static __device__ __forceinline__ bf16x8 ldw(const float* __restrict__ W, size_t off) {
    const float4 a = *(const float4*)(W + off);
    const float4 b = *(const float4*)(W + off + 4);
    union { uint4 u; bf16x8 v; } c;
    c.u.x = pk2bf(a.x, a.y); c.u.y = pk2bf(a.z, a.w);
    c.u.z = pk2bf(b.x, b.y); c.u.w = pk2bf(b.z, b.w);
    return c.v;
}

// ---------------------------------------------------------------------------
// QKV (R12's balanced version): LDS-staged LN + projection, inline fp32->bf16
// weight conversion. Blocks 0..767: z = gid/256 (0 Q/dec, 1 K/enc, 2 V/enc),
// 32 tokens each, every wave a uniform 4-nb / 16-MFMA chain.
// Blocks 768..839 convert wo/w1/w2 for the tail.
// ---------------------------------------------------------------------------
__global__ __launch_bounds__(256)
void qkv4_kernel(const float* __restrict__ enc, const float* __restrict__ dec,
                 const float* __restrict__ g_enc, const float* __restrict__ b_enc,
                 const float* __restrict__ g_dec, const float* __restrict__ b_dec,
                 const float* __restrict__ Wq, const float* __restrict__ Wk,
                 const float* __restrict__ Wv,
                 const float* __restrict__ bq, const float* __restrict__ bk,
                 const float* __restrict__ bv,
                 const float* __restrict__ Wo, const float* __restrict__ W1,
                 const float* __restrict__ W2,
                 unsigned short* __restrict__ wo, unsigned short* __restrict__ w1,
                 unsigned short* __restrict__ w2,
                 unsigned short* __restrict__ Qh, unsigned short* __restrict__ Kh,
                 unsigned short* __restrict__ Vt,
                 unsigned short* __restrict__ dec_lnb) {
    const int t = threadIdx.x;
    if (blockIdx.x >= 768) {
        // ---- weight conversion for the tail: wo(16384) w1(65536) w2(65536)
        const int e = ((int)blockIdx.x - 768) * 2048 + t * 8;
        const float* src; unsigned short* dst; int off;
        if (e < 16384)       { src = Wo; dst = wo; off = e; }
        else if (e < 81920)  { src = W1; dst = w1; off = e - 16384; }
        else                 { src = W2; dst = w2; off = e - 81920; }
        const float4 a = *(const float4*)(src + off);
        const float4 b = *(const float4*)(src + off + 4);
        uint4 p;
        p.x = pk2bf(a.x, a.y); p.y = pk2bf(a.z, a.w);
        p.z = pk2bf(b.x, b.y); p.w = pk2bf(b.z, b.w);
        *(uint4*)(dst + off) = p;
        return;
    }
    __shared__ float tile[128][33];
    __shared__ float mu_s[32], inv_s[32];
    const int z  = blockIdx.x >> 8;       // 0 Q/dec, 1 K/enc, 2 V/enc
    const int m0 = (blockIdx.x & 255) * 32;
    const int b  = m0 >> 12, n0 = m0 & 4095;
    const float* inb   = ((z == 0) ? dec : enc) + (size_t)b * 128 * N_;
    const float* gamma = (z == 0) ? g_dec : g_enc;
    const float* beta  = (z == 0) ? b_dec : b_enc;

    // stage: 128 chans x 32 tokens, 128B-coalesced along n
    {
        const int col = t & 31;
        const int r0  = t >> 5;
        #pragma unroll
        for (int j = 0; j < 16; ++j) {
            const int r = r0 + 8 * j;
            tile[r][col] = inb[(size_t)r * N_ + n0 + col];
        }
    }
    __syncthreads();
    // LN stats: 8 threads per token
    {
        const int tok = t >> 3;
        const int ln  = t & 7;
        float s = 0.f, ss = 0.f;
        for (int c = ln; c < 128; c += 8) {
            const float x = tile[c][tok];
            s += x; ss += x * x;
        }
        for (int m = 1; m < 8; m <<= 1) {
            s  += __shfl_xor(s, m);
            ss += __shfl_xor(ss, m);
        }
        if (ln == 0) {
            const float mu  = s * (1.f / 128.f);
            mu_s[tok]  = mu;
            inv_s[tok] = rsqrtf(ss * (1.f / 128.f) - mu * mu + 1e-5f);
        }
    }
    __syncthreads();

    const int wvx = t >> 6, lane = t & 63;
    const int l15 = lane & 15, quad = lane >> 4;
    const int tokgrp  = (wvx & 1) * 16;
    const int colbase = (wvx >> 1) * 64;
    const bool wrLN   = (z == 0) && ((wvx >> 1) == 0);
    const int tok = tokgrp + l15;
    const float mu  = mu_s[tok];
    const float inv = inv_s[tok];

    // build LN'd A-frags straight from LDS
    bf16x8 af[4];
    #pragma unroll
    for (int kk = 0; kk < 4; ++kk) {
        float y[8];
        #pragma unroll
        for (int j = 0; j < 8; ++j) {
            const int c = kk * 32 + quad * 8 + j;
            y[j] = (tile[c][tok] - mu) * inv * gamma[c] + beta[c];
        }
        union { uint4 u; bf16x8 v8; ushortx8 us; } cvt;
        cvt.u.x = pk2bf(y[0], y[1]); cvt.u.y = pk2bf(y[2], y[3]);
        cvt.u.z = pk2bf(y[4], y[5]); cvt.u.w = pk2bf(y[6], y[7]);
        af[kk] = cvt.v8;
        if (wrLN)
            *(ushortx8*)(dec_lnb + (size_t)(m0 + tok) * 128 + kk * 32 + quad * 8) = cvt.us;
    }

    const float* Wb   = (z == 0) ? Wq : ((z == 1) ? Wk : Wv);
    const float* bias = (z == 0) ? bq : ((z == 1) ? bk : bv);
    const float sc = (z == 0) ? (0.17677669529663687f * 1.4426950408889634f) : 1.f;
    const int nbase = n0 + tokgrp + quad * 4;

    #pragma unroll
    for (int nb = 0; nb < 4; ++nb) {
        const int col = colbase + nb * 16 + l15;
        f32x4 a = {0.f, 0.f, 0.f, 0.f};
        #pragma unroll
        for (int kk = 0; kk < 4; ++kk) {
            const bf16x8 wf = ldw(Wb, (size_t)col * 128 + kk * 32 + quad * 8);
            a = __builtin_amdgcn_mfma_f32_16x16x32_bf16(af[kk], wf, a, 0, 0, 0);
        }
        const int h = col >> 5, d = col & 31;
        const float bz = bias[col];
        if (z == 2) {
            ushort4 pk;
            pk.x = f2bf(a[0] + bz);
            pk.y = f2bf(a[1] + bz);
            pk.z = f2bf(a[2] + bz);
            pk.w = f2bf(a[3] + bz);
            *(ushort4*)(Vt + ((size_t)(b * NH_ + h) * 32 + d) * N_ + nbase) = pk;
        } else {
            unsigned short* dst = (z == 0) ? Qh : Kh;
            #pragma unroll
            for (int r = 0; r < 4; ++r)
                dst[((size_t)(b * NH_ + h) * N_ + nbase + r) * 32 + d] = f2bf((a[r] + bz) * sc);
        }
    }
}

// ---------------------------------------------------------------------------
// Attention v7 (R11-proven): split-K IN-BLOCK. 512-thr block = 8 waves =
// 8 K-splits of the SAME 64 queries; fp32 combine via LDS (reusing sP) ->
// final bf16 ctx write. Grid 512, XCD-affine (gid&7 == bh).
// ---------------------------------------------------------------------------
__global__ __launch_bounds__(512)
void attn_kernel7(const unsigned short* __restrict__ Qh,
                  const unsigned short* __restrict__ Kh,
                  const unsigned short* __restrict__ Vt,
                  unsigned short* __restrict__ ctx) {
    __shared__ alignas(16) unsigned short sP[8][64][72];  // 73728 B; reused fp32 [8][64][36]
    __shared__ float ldsL[8][64];

    const int gid  = blockIdx.x;
    const int bh   = gid & 7;
    const int qblk = gid >> 3;          // 0..63
    const int t  = threadIdx.x;
    const int wvx = t >> 6, lane = t & 63;
    const int l15 = lane & 15, quad = lane >> 4;
    const int s = wvx;
    const int qw = qblk * 64;
    const size_t hbse = (size_t)bh * N_ * 32;

    bf16x8 qf[4];
    #pragma unroll
    for (int f = 0; f < 4; ++f)
        qf[f] = *(const bf16x8*)(Qh + hbse + (size_t)(qw + f * 16 + l15) * 32 + quad * 8);

    const unsigned short* Kp = Kh + hbse;
    const unsigned short* Vp = Vt + (size_t)bh * 32 * N_;

    f32x4 o0[4], o1[4];
    float l[4];
    #pragma unroll
    for (int f = 0; f < 4; ++f) {
        o0[f] = f32x4{0.f, 0.f, 0.f, 0.f};
        o1[f] = f32x4{0.f, 0.f, 0.f, 0.f};
        l[f] = 0.f;
    }
    const f32x4 zero = {0.f, 0.f, 0.f, 0.f};

    const int kbeg = s * (N_ / SPLIT_);
    const int kend = kbeg + (N_ / SPLIT_);

    bf16x8 kf[4];
    #pragma unroll
    for (int c = 0; c < 4; ++c)
        kf[c] = *(const bf16x8*)(Kp + (size_t)(kbeg + c * 16 + l15) * 32 + quad * 8);

    for (int k0 = kbeg; k0 < kend; k0 += 64) {
        bf16x8 va[2], vb[2];
        #pragma unroll
        for (int s2 = 0; s2 < 2; ++s2) {
            va[s2] = *(const bf16x8*)(Vp + (size_t)l15 * N_        + k0 + s2 * 32 + quad * 8);
            vb[s2] = *(const bf16x8*)(Vp + (size_t)(16 + l15) * N_ + k0 + s2 * 32 + quad * 8);
        }
        const int kn = (k0 + 64 < kend) ? (k0 + 64) : kbeg;
        bf16x8 kfn[4];
        #pragma unroll
        for (int c = 0; c < 4; ++c)
            kfn[c] = *(const bf16x8*)(Kp + (size_t)(kn + c * 16 + l15) * 32 + quad * 8);

        #pragma unroll
        for (int f = 0; f < 4; ++f) {
            #pragma unroll
            for (int c = 0; c < 4; ++c) {
                const f32x4 sv = __builtin_amdgcn_mfma_f32_16x16x32_bf16(kf[c], qf[f], zero, 0, 0, 0);
                const float p0 = FAST_EXP2(sv[0]);
                const float p1 = FAST_EXP2(sv[1]);
                const float p2 = FAST_EXP2(sv[2]);
                const float p3 = FAST_EXP2(sv[3]);
                l[f] += (p0 + p1) + (p2 + p3);
                uint2 pk;
                pk.x = pk2bf(p0, p1);
                pk.y = pk2bf(p2, p3);
                *(uint2*)&sP[wvx][f * 16 + l15][c * 16 + quad * 4] = pk;
            }
        }
        #pragma unroll
        for (int f = 0; f < 4; ++f) {
            #pragma unroll
            for (int s2 = 0; s2 < 2; ++s2) {
                const bf16x8 pf = *(const bf16x8*)&sP[wvx][f * 16 + l15][s2 * 32 + quad * 8];
                o0[f] = __builtin_amdgcn_mfma_f32_16x16x32_bf16(va[s2], pf, o0[f], 0, 0, 0);
                o1[f] = __builtin_amdgcn_mfma_f32_16x16x32_bf16(vb[s2], pf, o1[f], 0, 0, 0);
            }
        }
        #pragma unroll
        for (int c = 0; c < 4; ++c) kf[c] = kfn[c];
    }

    float lf4[4];
    #pragma unroll
    for (int f = 0; f < 4; ++f) {
        float lf = l[f];
        lf += __shfl_xor(lf, 16);
        lf += __shfl_xor(lf, 32);
        lf4[f] = lf;
    }

    __syncthreads();
    float* ldsO = (float*)&sP[0][0][0];   // [8][64][36]
    #pragma unroll
    for (int f = 0; f < 4; ++f) {
        const int q = f * 16 + l15;
        float* row = ldsO + ((size_t)s * 64 + q) * 36;
        *(f32x4*)(row + quad * 4)      = o0[f];
        *(f32x4*)(row + 16 + quad * 4) = o1[f];
        if (quad == 0) ldsL[s][q] = lf4[f];
    }
    __syncthreads();

    const int tok = t >> 3;
    const int d0  = (t & 7) * 4;
    f32x4 sum = {0.f, 0.f, 0.f, 0.f};
    float lsum = 0.f;
    #pragma unroll
    for (int w = 0; w < 8; ++w) {
        sum  += *(const f32x4*)(ldsO + ((size_t)w * 64 + tok) * 36 + d0);
        lsum += ldsL[w][tok];
    }
    const float inv = 1.f / lsum;
    uint2 pk;
    pk.x = pk2bf(sum[0] * inv, sum[1] * inv);
    pk.y = pk2bf(sum[2] * inv, sum[3] * inv);
    const int b = bh >> 2, h = bh & 3;
    *(uint2*)(ctx + ((size_t)(b * N_ + qw + tok)) * 128 + h * 32 + d0) = pk;
}

// ---------------------------------------------------------------------------
// Fused tail v4 (R11-proven): Wo + residual + LN + FFN1(gelu) + FFN2 +
// residual -> [B,128,N] fp32. Split-K per phase (8-way ILP accumulators),
// bf16 partial buffer (18.4 KB) -> 4 blocks/CU. 512 blocks x 16 tokens.
// ---------------------------------------------------------------------------
__global__ __launch_bounds__(256)
void fused_tail4_kernel(const unsigned short* __restrict__ ctx,
                        const unsigned short* __restrict__ wo,
                        const float* __restrict__ bo,
                        const unsigned short* __restrict__ decb,
                        const float* __restrict__ g, const float* __restrict__ be,
                        const unsigned short* __restrict__ w1,
                        const float* __restrict__ b1,
                        const unsigned short* __restrict__ w2,
                        const float* __restrict__ b2,
                        float* __restrict__ out) {
    __shared__ alignas(16) unsigned short sredb[4][64][36];    // 18.4 KB
    __shared__ float sln[4][2][16];
    __shared__ alignas(16) unsigned short hb_lds[16][136];
    __shared__ alignas(16) unsigned short smid[16][536];
    const int t = threadIdx.x;
    const int wv = t >> 6, lane = t & 63;
    const int l15 = lane & 15, quad = lane >> 4;
    const int m0 = blockIdx.x * 16;

    // ---- A-frag: head wv chans of this token, single 16B load
    const int tokA = m0 + l15;
    const bf16x8 af = *(const bf16x8*)(ctx + (size_t)tokA * 128 + wv * 32 + quad * 8);

    // ---- Wo partials (K = chans of head wv), bf16-packed to LDS
    #pragma unroll
    for (int nb = 0; nb < 8; ++nb) {
        const bf16x8 wf = *(const bf16x8*)(wo + (size_t)(nb * 16 + l15) * 128
                                           + wv * 32 + quad * 8);
        const f32x4 a = __builtin_amdgcn_mfma_f32_16x16x32_bf16(
            af, wf, f32x4{0.f, 0.f, 0.f, 0.f}, 0, 0, 0);
        uint2 p;
        p.x = pk2bf(a[0], a[1]);
        p.y = pk2bf(a[2], a[3]);
        *(uint2*)&sredb[wv][lane][nb * 4] = p;
    }
    __syncthreads();

    // ---- reduce own col-slice, + bias + residual -> out1 (regs)
    float v[2][4];
    #pragma unroll
    for (int lnb = 0; lnb < 2; ++lnb) {
        const int nbg = 2 * wv + lnb;
        f32x4 p = {0.f, 0.f, 0.f, 0.f};
        #pragma unroll
        for (int w = 0; w < 4; ++w) {
            const ushort4 u = *(const ushort4*)&sredb[w][lane][nbg * 4];
            p[0] += bf2f(u.x); p[1] += bf2f(u.y);
            p[2] += bf2f(u.z); p[3] += bf2f(u.w);
        }
        const int col = nbg * 16 + l15;
        const float bz = bo[col];
        #pragma unroll
        for (int r = 0; r < 4; ++r) {
            const int tok = m0 + quad * 4 + r;
            v[lnb][r] = p[r] + bz + bf2f(decb[(size_t)tok * 128 + col]);
        }
    }

    // ---- LN partial sums over this wave's 32 cols
    {
        float s[4], ss[4];
        #pragma unroll
        for (int r = 0; r < 4; ++r) {
            float a = v[0][r] + v[1][r];
            float b = v[0][r] * v[0][r] + v[1][r] * v[1][r];
            for (int m = 1; m < 16; m <<= 1) {
                a += __shfl_xor(a, m);
                b += __shfl_xor(b, m);
            }
            s[r] = a; ss[r] = b;
        }
        if (l15 == 0) {
            #pragma unroll
            for (int r = 0; r < 4; ++r) {
                sln[wv][0][quad * 4 + r] = s[r];
                sln[wv][1][quad * 4 + r] = ss[r];
            }
        }
    }
    __syncthreads();

    // ---- full LN stats, normalize own slice -> hb_lds
    {
        #pragma unroll
        for (int r = 0; r < 4; ++r) {
            const int tk = quad * 4 + r;
            const float stot  = sln[0][0][tk] + sln[1][0][tk] + sln[2][0][tk] + sln[3][0][tk];
            const float sstot = sln[0][1][tk] + sln[1][1][tk] + sln[2][1][tk] + sln[3][1][tk];
            const float mu  = stot * (1.f / 128.f);
            const float inv = rsqrtf(sstot * (1.f / 128.f) - mu * mu + 1e-5f);
            #pragma unroll
            for (int lnb = 0; lnb < 2; ++lnb) {
                const int col = (2 * wv + lnb) * 16 + l15;
                hb_lds[tk][col] = f2bf((v[lnb][r] - mu) * inv * g[col] + be[col]);
            }
        }
    }
    __syncthreads();

    // ---- FFN1: wave covers cols [wv*128, wv*128+128)
    bf16x8 hf[4];
    #pragma unroll
    for (int kk = 0; kk < 4; ++kk)
        hf[kk] = *(const bf16x8*)&hb_lds[l15][kk * 32 + quad * 8];
    #pragma unroll
    for (int nb = 0; nb < 8; ++nb) {
        const int col = wv * 128 + nb * 16 + l15;
        f32x4 a = {0.f, 0.f, 0.f, 0.f};
        #pragma unroll
        for (int kk = 0; kk < 4; ++kk) {
            const bf16x8 wf = *(const bf16x8*)(w1 + (size_t)col * 128 + kk * 32 + quad * 8);
            a = __builtin_amdgcn_mfma_f32_16x16x32_bf16(hf[kk], wf, a, 0, 0, 0);
        }
        const float bz = b1[col];
        #pragma unroll
        for (int r = 0; r < 4; ++r) {
            float x = a[r] + bz;
            x = 0.5f * x * (1.f + erff(x * 0.70710678118f));
            smid[quad * 4 + r][col] = f2bf(x);
        }
    }
    __syncthreads();

    // ---- FFN2: wave accumulates K-quarter [wv*128, wv*128+128)
    f32x4 acc[8];
    #pragma unroll
    for (int nb = 0; nb < 8; ++nb) acc[nb] = f32x4{0.f, 0.f, 0.f, 0.f};
    #pragma unroll
    for (int kk = 0; kk < 4; ++kk) {
        const bf16x8 af2 = *(const bf16x8*)&smid[l15][wv * 128 + kk * 32 + quad * 8];
        #pragma unroll
        for (int nb = 0; nb < 8; ++nb) {
            const bf16x8 wf = *(const bf16x8*)(w2 + (size_t)(nb * 16 + l15) * 512
                                               + wv * 128 + kk * 32 + quad * 8);
            acc[nb] = __builtin_amdgcn_mfma_f32_16x16x32_bf16(af2, wf, acc[nb], 0, 0, 0);
        }
    }
    __syncthreads();
    #pragma unroll
    for (int nb = 0; nb < 8; ++nb) {
        uint2 p;
        p.x = pk2bf(acc[nb][0], acc[nb][1]);
        p.y = pk2bf(acc[nb][2], acc[nb][3]);
        *(uint2*)&sredb[wv][lane][nb * 4] = p;
    }
    __syncthreads();

    // ---- reduce own col-slice, + b2 + out1 residual, store [B,128,N] fp32
    {
        const int b = m0 >> 12;
        const int nb0 = (m0 & 4095) + quad * 4;
        #pragma unroll
        for (int lnb = 0; lnb < 2; ++lnb) {
            const int nbg = 2 * wv + lnb;
            f32x4 p = {0.f, 0.f, 0.f, 0.f};
            #pragma unroll
            for (int w = 0; w < 4; ++w) {
                const ushort4 u = *(const ushort4*)&sredb[w][lane][nbg * 4];
                p[0] += bf2f(u.x); p[1] += bf2f(u.y);
                p[2] += bf2f(u.z); p[3] += bf2f(u.w);
            }
            const int col = nbg * 16 + l15;
            const float bz = b2[col];
            f32x4 res;
            #pragma unroll
            for (int r = 0; r < 4; ++r)
                res[r] = p[r] + bz + v[lnb][r];
            *(f32x4*)&out[((size_t)(b * 128 + col)) * N_ + nb0] = res;
        }
    }
}

// ---------------------------------------------------------------------------
extern "C" void kernel_launch(void* const* d_in, const int* in_sizes, int n_in,
                              void* d_out, int out_size, void* d_ws, size_t ws_size,
                              hipStream_t stream) {
    const float* enc   = (const float*)d_in[0];
    const float* dec   = (const float*)d_in[1];
    const float* Wq    = (const float*)d_in[2];
    const float* bq    = (const float*)d_in[3];
    const float* Wk    = (const float*)d_in[4];
    const float* bk    = (const float*)d_in[5];
    const float* Wv    = (const float*)d_in[6];
    const float* bv    = (const float*)d_in[7];
    const float* Wo    = (const float*)d_in[8];
    const float* bo    = (const float*)d_in[9];
    const float* g_enc = (const float*)d_in[10];
    const float* b_enc = (const float*)d_in[11];
    const float* g_dec = (const float*)d_in[12];
    const float* b_dec = (const float*)d_in[13];
    const float* g_out = (const float*)d_in[14];
    const float* b_out = (const float*)d_in[15];
    const float* W1    = (const float*)d_in[16];
    const float* b1    = (const float*)d_in[17];
    const float* W2    = (const float*)d_in[18];
    const float* b2    = (const float*)d_in[19];
    float* out = (float*)d_out;
    char*  W   = (char*)d_ws;

    // workspace layout (<= 13 MB, subset of prior passing footprint)
    unsigned short* wob = (unsigned short*)(W);          // 32 KB
    unsigned short* w1b = wob + 16384;                   // 128 KB
    unsigned short* w2b = w1b + 65536;                   // 128 KB (ends 288 KB)
    unsigned short* dec_lnb = (unsigned short*)(W + (2560ull << 10));   // [2.5, 4.5) MB
    unsigned short* Qh      = (unsigned short*)(W + (4608ull << 10));   // [4.5, 6.5)
    unsigned short* Kh      = (unsigned short*)(W + (6656ull << 10));   // [6.5, 8.5)
    unsigned short* Vt      = (unsigned short*)(W + (8704ull << 10));   // [8.5, 10.5)
    unsigned short* ctx     = (unsigned short*)(W + (10752ull << 10));  // 2 MB

    // QKV (+inline LN, inline wq/wk/wv cvt) + tail-weight conversion blocks
    qkv4_kernel<<<768 + 72, 256, 0, stream>>>(
        enc, dec, g_enc, b_enc, g_dec, b_dec, Wq, Wk, Wv, bq, bk, bv,
        Wo, W1, W2, wob, w1b, w2b, Qh, Kh, Vt, dec_lnb);

    // 512 blocks x 512 thr, XCD-affine (gid&7 == bh); in-block split combine
    attn_kernel7<<<512, 512, 0, stream>>>(Qh, Kh, Vt, ctx);

    fused_tail4_kernel<<<512, 256, 0, stream>>>(ctx, wob, bo, dec_lnb,
                                                g_out, b_out, w1b, b1, w2b, b2, out);
}